// Round 1
// baseline (3569.890 us; speedup 1.0000x reference)
//
#include <hip/hip_runtime.h>
#include <hip/hip_bf16.h>
#include <math.h>

// Problem constants (match reference)
#define BATCH   4
#define TSEQ    1024
#define DMODEL  1024
#define NHEAD   16
#define DHEAD   64
#define HFF     4096
#define MROWS   (BATCH * TSEQ)   // 4096

// ---------------------------------------------------------------------------
// GEMM: C[M,N] = A[M,K] @ W[N,K]^T + bias[N]  (+ residual R[M,N]) (+ ReLU)
// Both A and W row-major with K contiguous (the x@w.T layout).
// Tile 128x64, 256 threads, 8x4 per thread, BK=32, k-major LDS (padded).
// ---------------------------------------------------------------------------
#define GBM 128
#define GBN 64
#define GBK 32

template<bool RES, bool RELU>
__global__ __launch_bounds__(256, 2)
void gemm_kernel(const float* __restrict__ A, const float* __restrict__ W,
                 const float* __restrict__ bias, const float* __restrict__ R,
                 float* __restrict__ C, int M, int N, int K)
{
    __shared__ float As[GBK][GBM + 4];   // k-major, pad to break write conflicts
    __shared__ float Ws[GBK][GBN + 4];

    const int t  = threadIdx.x;
    const int m0 = blockIdx.y * GBM;
    const int n0 = blockIdx.x * GBN;
    const int tm = (t & 15) * 8;     // 16 groups cover 128 rows
    const int tn = (t >> 4) * 4;     // 16 groups cover 64 cols
    const int kq = (t & 7) * 4;      // k-quad for staging
    const int rr = t >> 3;           // 0..31 staging row

    float acc[8][4];
#pragma unroll
    for (int i = 0; i < 8; ++i)
#pragma unroll
        for (int j = 0; j < 4; ++j) acc[i][j] = 0.f;

    const float* Ap = A + (size_t)(m0 + rr) * K + kq;
    const float* Wp = W + (size_t)(n0 + rr) * K + kq;

    for (int k0 = 0; k0 < K; k0 += GBK) {
        // stage A tile (128 x 32) transposed into As[k][m]
#pragma unroll
        for (int p = 0; p < 4; ++p) {
            float4 av = *(const float4*)(Ap + (size_t)(p * 32) * K + k0);
            int m = rr + p * 32;
            As[kq + 0][m] = av.x; As[kq + 1][m] = av.y;
            As[kq + 2][m] = av.z; As[kq + 3][m] = av.w;
        }
        // stage W tile (64 x 32) transposed into Ws[k][n]
#pragma unroll
        for (int p = 0; p < 2; ++p) {
            float4 wv = *(const float4*)(Wp + (size_t)(p * 32) * K + k0);
            int n = rr + p * 32;
            Ws[kq + 0][n] = wv.x; Ws[kq + 1][n] = wv.y;
            Ws[kq + 2][n] = wv.z; Ws[kq + 3][n] = wv.w;
        }
        __syncthreads();

#pragma unroll
        for (int k = 0; k < GBK; ++k) {
            float4 a0 = *(const float4*)&As[k][tm];
            float4 a1 = *(const float4*)&As[k][tm + 4];
            float4 b0 = *(const float4*)&Ws[k][tn];
            float a[8] = {a0.x, a0.y, a0.z, a0.w, a1.x, a1.y, a1.z, a1.w};
            float bv[4] = {b0.x, b0.y, b0.z, b0.w};
#pragma unroll
            for (int i = 0; i < 8; ++i)
#pragma unroll
                for (int j = 0; j < 4; ++j)
                    acc[i][j] = fmaf(a[i], bv[j], acc[i][j]);
        }
        __syncthreads();
    }

    const float4 bb = *(const float4*)(bias + n0 + tn);
#pragma unroll
    for (int i = 0; i < 8; ++i) {
        const size_t off = (size_t)(m0 + tm + i) * N + n0 + tn;
        float4 v;
        v.x = acc[i][0] + bb.x; v.y = acc[i][1] + bb.y;
        v.z = acc[i][2] + bb.z; v.w = acc[i][3] + bb.w;
        if (RES) {
            float4 rv = *(const float4*)(R + off);
            v.x += rv.x; v.y += rv.y; v.z += rv.z; v.w += rv.w;
        }
        if (RELU) {
            v.x = fmaxf(v.x, 0.f); v.y = fmaxf(v.y, 0.f);
            v.z = fmaxf(v.z, 0.f); v.w = fmaxf(v.w, 0.f);
        }
        *(float4*)(C + off) = v;
    }
}

// ---------------------------------------------------------------------------
// Flash-style attention, fp32. One q-row per thread, 128 threads/block.
// Q/K/V/O layout: (B, T, D) with head h occupying columns h*64..h*64+63.
// probs = softmax((q.k - (1-mask)*1e10) / 32), causal masks k > qrow.
// ---------------------------------------------------------------------------
#define KT 32

template<bool CAUSAL>
__global__ __launch_bounds__(128, 2)
void attn_kernel(const float* __restrict__ Qb, const float* __restrict__ Kb,
                 const float* __restrict__ Vb, const float* __restrict__ maskp,
                 float* __restrict__ Ob)
{
    __shared__ float Ks[KT][DHEAD];
    __shared__ float Vs[KT][DHEAD];
    __shared__ float Ms[KT];

    const int bn = blockIdx.y;
    const int b  = bn >> 4;        // / NHEAD
    const int h  = bn & 15;
    const int qrow = blockIdx.x * 128 + threadIdx.x;
    const size_t rowbase = (size_t)(b * TSEQ + qrow) * DMODEL + h * DHEAD;

    float q[DHEAD];
#pragma unroll
    for (int d4 = 0; d4 < DHEAD / 4; ++d4) {
        float4 v = *(const float4*)(Qb + rowbase + d4 * 4);
        q[d4 * 4 + 0] = v.x; q[d4 * 4 + 1] = v.y;
        q[d4 * 4 + 2] = v.z; q[d4 * 4 + 3] = v.w;
    }
    float o[DHEAD];
#pragma unroll
    for (int d = 0; d < DHEAD; ++d) o[d] = 0.f;
    float mx = -3.0e38f, l = 0.f;

    const int kend = CAUSAL ? (blockIdx.x * 128 + 128) : TSEQ;
    const float* mrow = maskp + b * TSEQ;

    for (int kt = 0; kt < kend; kt += KT) {
        // cooperative stage of K/V tile (32 x 64)
#pragma unroll
        for (int p = 0; p < 4; ++p) {
            int fidx = threadIdx.x + p * 128;     // 0..511 float4 slots
            int r  = fidx >> 4;
            int c4 = (fidx & 15) * 4;
            size_t gb = (size_t)(b * TSEQ + kt + r) * DMODEL + h * DHEAD + c4;
            *(float4*)&Ks[r][c4] = *(const float4*)(Kb + gb);
            *(float4*)&Vs[r][c4] = *(const float4*)(Vb + gb);
        }
        if (threadIdx.x < KT) Ms[threadIdx.x] = mrow[kt + threadIdx.x];
        __syncthreads();

        const int jend = CAUSAL ? min(KT, qrow - kt + 1) : KT;
        for (int j = 0; j < jend; ++j) {
            float dot = 0.f;
#pragma unroll
            for (int d4 = 0; d4 < DHEAD / 4; ++d4) {
                float4 kk = *(const float4*)&Ks[j][d4 * 4];
                dot = fmaf(q[d4 * 4 + 0], kk.x, dot);
                dot = fmaf(q[d4 * 4 + 1], kk.y, dot);
                dot = fmaf(q[d4 * 4 + 2], kk.z, dot);
                dot = fmaf(q[d4 * 4 + 3], kk.w, dot);
            }
            float s = (dot - (1.0f - Ms[j]) * 1.0e10f) * (1.0f / 32.0f);
            if (s > mx) {                     // rescale only when max grows
                const float c = __expf(mx - s);
                l *= c;
#pragma unroll
                for (int d = 0; d < DHEAD; ++d) o[d] *= c;
                mx = s;
            }
            const float p = __expf(s - mx);
            l += p;
#pragma unroll
            for (int d4 = 0; d4 < DHEAD / 4; ++d4) {
                float4 vv = *(const float4*)&Vs[j][d4 * 4];
                o[d4 * 4 + 0] = fmaf(p, vv.x, o[d4 * 4 + 0]);
                o[d4 * 4 + 1] = fmaf(p, vv.y, o[d4 * 4 + 1]);
                o[d4 * 4 + 2] = fmaf(p, vv.z, o[d4 * 4 + 2]);
                o[d4 * 4 + 3] = fmaf(p, vv.w, o[d4 * 4 + 3]);
            }
        }
        __syncthreads();
    }

    const float inv = 1.0f / l;
#pragma unroll
    for (int d4 = 0; d4 < DHEAD / 4; ++d4) {
        float4 v;
        v.x = o[d4 * 4 + 0] * inv; v.y = o[d4 * 4 + 1] * inv;
        v.z = o[d4 * 4 + 2] * inv; v.w = o[d4 * 4 + 3] * inv;
        *(float4*)(Ob + rowbase + d4 * 4) = v;
    }
}

// ---------------------------------------------------------------------------
// LayerNorm matching reference: unbiased var (/(D-1)), eps added to STD.
// One block (256 threads) per row of 1024.
// ---------------------------------------------------------------------------
__inline__ __device__ float block_sum256(float v, float* sm)
{
#pragma unroll
    for (int off = 32; off > 0; off >>= 1) v += __shfl_down(v, off, 64);
    const int lane = threadIdx.x & 63, w = threadIdx.x >> 6;
    if (lane == 0) sm[w] = v;
    __syncthreads();
    float r = sm[0] + sm[1] + sm[2] + sm[3];
    __syncthreads();
    return r;
}

__global__ __launch_bounds__(256)
void ln_kernel(const float* __restrict__ X, const float* __restrict__ g,
               const float* __restrict__ be, float* __restrict__ Y)
{
    __shared__ float sm[4];
    const int row = blockIdx.x;
    const size_t base = (size_t)row * DMODEL + threadIdx.x * 4;
    const float4 xv = *(const float4*)(X + base);

    float s = xv.x + xv.y + xv.z + xv.w;
    s = block_sum256(s, sm);
    const float mean = s * (1.0f / (float)DMODEL);

    float4 dx;
    dx.x = xv.x - mean; dx.y = xv.y - mean; dx.z = xv.z - mean; dx.w = xv.w - mean;
    float s2 = dx.x * dx.x + dx.y * dx.y + dx.z * dx.z + dx.w * dx.w;
    s2 = block_sum256(s2, sm);
    const float rs = 1.0f / (sqrtf(s2 * (1.0f / (float)(DMODEL - 1))) + 1e-6f);

    const float4 gv = *(const float4*)(g + threadIdx.x * 4);
    const float4 bv = *(const float4*)(be + threadIdx.x * 4);
    float4 y;
    y.x = gv.x * dx.x * rs + bv.x;
    y.y = gv.y * dx.y * rs + bv.y;
    y.z = gv.z * dx.z * rs + bv.z;
    y.w = gv.w * dx.w * rs + bv.w;
    *(float4*)(Y + base) = y;
}

// ---------------------------------------------------------------------------
extern "C" void kernel_launch(void* const* d_in, const int* in_sizes, int n_in,
                              void* d_out, int out_size, void* d_ws, size_t ws_size,
                              hipStream_t stream)
{
    (void)in_sizes; (void)n_in; (void)out_size; (void)ws_size;

    const float* x        = (const float*)d_in[0];
    const float* enc      = (const float*)d_in[1];
    const float* mask_src = (const float*)d_in[2];
    const float* mask_trg = (const float*)d_in[3];
    const float* sa_wq = (const float*)d_in[4];  const float* sa_bq = (const float*)d_in[5];
    const float* sa_wk = (const float*)d_in[6];  const float* sa_bk = (const float*)d_in[7];
    const float* sa_wv = (const float*)d_in[8];  const float* sa_bv = (const float*)d_in[9];
    const float* sa_wo = (const float*)d_in[10]; const float* sa_bo = (const float*)d_in[11];
    const float* sa_g  = (const float*)d_in[12]; const float* sa_b  = (const float*)d_in[13];
    const float* ca_wq = (const float*)d_in[14]; const float* ca_bq = (const float*)d_in[15];
    const float* ca_wk = (const float*)d_in[16]; const float* ca_bk = (const float*)d_in[17];
    const float* ca_wv = (const float*)d_in[18]; const float* ca_bv = (const float*)d_in[19];
    const float* ca_wo = (const float*)d_in[20]; const float* ca_bo = (const float*)d_in[21];
    const float* ca_g  = (const float*)d_in[22]; const float* ca_b  = (const float*)d_in[23];
    const float* ff_w1 = (const float*)d_in[24]; const float* ff_b1 = (const float*)d_in[25];
    const float* ff_w2 = (const float*)d_in[26]; const float* ff_b2 = (const float*)d_in[27];
    const float* ff_g  = (const float*)d_in[28]; const float* ff_b  = (const float*)d_in[29];

    float* ws = (float*)d_ws;
    const size_t S = (size_t)MROWS * DMODEL;      // 4M floats = 16MB
    float* s0 = ws;             // Q / h_pre / attn2-out / F1(part)
    float* s1 = ws + S;         // K  / F1(part)
    float* s2 = ws + 2 * S;     // V  / F1(part)
    float* s3 = ws + 3 * S;     // attn-out / Q2 / F1(part)
    float* s4 = ws + 4 * S;     // H1, later ff_out_pre
    float* s5 = ws + 5 * S;     // H2
    // total workspace: 6*S*4 = 96 MB

    dim3 blk(256);
    dim3 g1024(DMODEL / GBN, MROWS / GBM);   // (16, 32)
    dim3 gff  (HFF    / GBN, MROWS / GBM);   // (64, 32)
    dim3 ablk(128);
    dim3 agrid(TSEQ / 128, BATCH * NHEAD);   // (8, 64)

    // ---- self-attention (causal) ----
    gemm_kernel<false, false><<<g1024, blk, 0, stream>>>(x, sa_wq, sa_bq, nullptr, s0, MROWS, DMODEL, DMODEL);
    gemm_kernel<false, false><<<g1024, blk, 0, stream>>>(x, sa_wk, sa_bk, nullptr, s1, MROWS, DMODEL, DMODEL);
    gemm_kernel<false, false><<<g1024, blk, 0, stream>>>(x, sa_wv, sa_bv, nullptr, s2, MROWS, DMODEL, DMODEL);
    attn_kernel<true><<<agrid, ablk, 0, stream>>>(s0, s1, s2, mask_trg, s3);
    gemm_kernel<true, false><<<g1024, blk, 0, stream>>>(s3, sa_wo, sa_bo, x, s0, MROWS, DMODEL, DMODEL);
    ln_kernel<<<MROWS, 256, 0, stream>>>(s0, sa_g, sa_b, s4);             // H1 = s4

    // ---- cross-attention ----
    gemm_kernel<false, false><<<g1024, blk, 0, stream>>>(s4,  ca_wq, ca_bq, nullptr, s3, MROWS, DMODEL, DMODEL);
    gemm_kernel<false, false><<<g1024, blk, 0, stream>>>(enc, ca_wk, ca_bk, nullptr, s1, MROWS, DMODEL, DMODEL);
    gemm_kernel<false, false><<<g1024, blk, 0, stream>>>(enc, ca_wv, ca_bv, nullptr, s2, MROWS, DMODEL, DMODEL);
    attn_kernel<false><<<agrid, ablk, 0, stream>>>(s3, s1, s2, mask_src, s0);
    gemm_kernel<true, false><<<g1024, blk, 0, stream>>>(s0, ca_wo, ca_bo, s4, s3, MROWS, DMODEL, DMODEL);
    ln_kernel<<<MROWS, 256, 0, stream>>>(s3, ca_g, ca_b, s5);             // H2 = s5

    // ---- feedforward ----
    // F1 = relu(H2 @ w1^T + b1): 4096x4096, occupies s0..s3 (4*S floats)
    gemm_kernel<false, true><<<gff, blk, 0, stream>>>(s5, ff_w1, ff_b1, nullptr, s0, MROWS, HFF, DMODEL);
    gemm_kernel<true, false><<<g1024, blk, 0, stream>>>(s0, ff_w2, ff_b2, s5, s4, MROWS, DMODEL, HFF);
    ln_kernel<<<MROWS, 256, 0, stream>>>(s4, ff_g, ff_b, (float*)d_out);
}

// Round 2
// 934.191 us; speedup vs baseline: 3.8214x; 3.8214x over previous
//
#include <hip/hip_runtime.h>
#include <hip/hip_bf16.h>
#include <math.h>
#include <stdint.h>

#define BATCH   4
#define TSEQ    1024
#define DMODEL  1024
#define NHEAD   16
#define DHEAD   64
#define HFF     4096
#define MROWS   (BATCH * TSEQ)   // 4096

typedef _Float16 f16;
typedef __attribute__((ext_vector_type(2))) _Float16 f16x2;
typedef __attribute__((ext_vector_type(4))) _Float16 f16x4;
typedef __attribute__((ext_vector_type(8))) _Float16 f16x8;
typedef __attribute__((ext_vector_type(4))) float    f32x4;

// ---------------------------------------------------------------------------
// fp32 -> f16 conversion (vectorized, 8 elems/thread)
// ---------------------------------------------------------------------------
__global__ __launch_bounds__(256)
void cvt_f32_f16(const float* __restrict__ in, f16* __restrict__ out, int n)
{
    const int i = (blockIdx.x * 256 + threadIdx.x) * 8;
    if (i < n) {
        const float4 a = *(const float4*)(in + i);
        const float4 b = *(const float4*)(in + i + 4);
        f16x8 o;
        o[0] = (_Float16)a.x; o[1] = (_Float16)a.y; o[2] = (_Float16)a.z; o[3] = (_Float16)a.w;
        o[4] = (_Float16)b.x; o[5] = (_Float16)b.y; o[6] = (_Float16)b.z; o[7] = (_Float16)b.w;
        *(f16x8*)(out + i) = o;
    }
}

// ---------------------------------------------------------------------------
// f16 MFMA GEMM: C[M,N](f16) = A[M,K](f16) @ W[N,K]^T(f16) + bias (+res)(+relu)
// Tile 128 x TN, BK=32, 256 threads = 4 waves (2x2), 2-phase LDS double-buffer,
// staging via global_load_lds width=16. mfma_f32_16x16x32_f16.
// ---------------------------------------------------------------------------
template<int TN, bool RES, bool RELU>
__global__ __launch_bounds__(256, 2)
void hgemm(const f16* __restrict__ A, const f16* __restrict__ Wt,
           const float* __restrict__ bias, const f16* __restrict__ Rm,
           f16* __restrict__ C, int M, int N, int K)
{
    constexpr int TM = 128, TK = 32;
    constexpr int NB = TN / 32;              // b-frags per wave
    constexpr int AISS = (TM * TK) / (256 * 8);   // 2
    constexpr int BISS = (TN * TK) / (256 * 8);   // 1 or 2
    __shared__ alignas(16) f16 As[2][TM * TK];
    __shared__ alignas(16) f16 Bs[2][TN * TK];

    const int t = threadIdx.x, ln = t & 63, wv = t >> 6;
    const int wr = wv >> 1, wc = wv & 1;
    const size_t m0 = (size_t)blockIdx.y * TM, n0 = (size_t)blockIdx.x * TN;

    f32x4 acc[4][NB];
#pragma unroll
    for (int i = 0; i < 4; ++i)
#pragma unroll
        for (int j = 0; j < NB; ++j) acc[i][j] = (f32x4){0.f, 0.f, 0.f, 0.f};

    const f16* Ag = A + (m0 + (t >> 2)) * (size_t)K + (t & 3) * 8;
    const f16* Bg = Wt + (n0 + (t >> 2)) * (size_t)K + (t & 3) * 8;

    auto stage = [&](int buf, int k0) {
#pragma unroll
        for (int i = 0; i < AISS; ++i)
            __builtin_amdgcn_global_load_lds(
                (const __attribute__((address_space(1))) unsigned int*)(Ag + (size_t)(i * 64) * K + k0),
                (__attribute__((address_space(3))) unsigned int*)(&As[buf][(i * 256 + wv * 64) * 8]),
                16, 0, 0);
#pragma unroll
        for (int i = 0; i < BISS; ++i)
            __builtin_amdgcn_global_load_lds(
                (const __attribute__((address_space(1))) unsigned int*)(Bg + (size_t)(i * 64) * K + k0),
                (__attribute__((address_space(3))) unsigned int*)(&Bs[buf][(i * 256 + wv * 64) * 8]),
                16, 0, 0);
    };

    stage(0, 0);
    __syncthreads();
    int buf = 0;
    for (int k0 = 0; k0 < K; k0 += TK) {
        if (k0 + TK < K) stage(buf ^ 1, k0 + TK);
        f16x8 af[4], bf[NB];
        const f16* Ab = As[buf];
        const f16* Bb = Bs[buf];
#pragma unroll
        for (int i = 0; i < 4; ++i)
            af[i] = *(const f16x8*)(Ab + (wr * 64 + i * 16 + (ln & 15)) * TK + (ln >> 4) * 8);
#pragma unroll
        for (int j = 0; j < NB; ++j)
            bf[j] = *(const f16x8*)(Bb + (wc * (TN / 2) + j * 16 + (ln & 15)) * TK + (ln >> 4) * 8);
#pragma unroll
        for (int i = 0; i < 4; ++i)
#pragma unroll
            for (int j = 0; j < NB; ++j)
                acc[i][j] = __builtin_amdgcn_mfma_f32_16x16x32_f16(af[i], bf[j], acc[i][j], 0, 0, 0);
        __syncthreads();
        buf ^= 1;
    }

    const int colbase = (int)n0 + wc * (TN / 2) + (ln & 15);
    const int rowbase = (int)m0 + wr * 64 + (ln >> 4) * 4;
#pragma unroll
    for (int i = 0; i < 4; ++i) {
#pragma unroll
        for (int j = 0; j < NB; ++j) {
            const int col = colbase + j * 16;
            const float bj = bias[col];
#pragma unroll
            for (int r = 0; r < 4; ++r) {
                const int row = rowbase + i * 16 + r;
                float v = acc[i][j][r] + bj;
                if (RES) v += (float)Rm[(size_t)row * N + col];
                if (RELU) v = fmaxf(v, 0.f);
                C[(size_t)row * N + col] = (f16)v;
            }
        }
    }
}

// ---------------------------------------------------------------------------
// Flash attention, f16 in/out, fp32 math. Block = 256 thr = 4 waves.
// Block covers 128 q-rows: lane ln owns rows (qblk+ln, qblk+64+ln).
// Waves = 4-way k-split (wave w takes k-tiles w, w+4, ...), KT=32.
// K tile f16 (global_load_lds), V tile f32 (converted at stage), both per-wave.
// Online softmax with deferred-max (threshold 8). LDS merge across waves.
// ---------------------------------------------------------------------------
template<bool CAUSAL>
__global__ __launch_bounds__(256, 2)
void attn(const f16* __restrict__ Qp, int qstr,
          const f16* __restrict__ Kp, int kstr,
          const f16* __restrict__ Vp, int vstr,
          const float* __restrict__ maskp,
          f16* __restrict__ Op)
{
    __shared__ alignas(16) char smem[49152];   // 4 waves * (4KB K + 8KB V); merge aliases
    const int t = threadIdx.x, ln = t & 63, wv = t >> 6;
    const int bh = blockIdx.y, b = bh >> 4, h = bh & 15;
    const int qblk = blockIdx.x * 128;
    const int bT = b * TSEQ;

    f16*   Ks = (f16*)(smem + wv * 12288);            // [32][64] f16
    float* Vs = (float*)(smem + wv * 12288 + 4096);   // [32][64] f32

    const int r0 = qblk + ln, r1 = r0 + 64;

    f16x8 q0[8], q1[8];
    {
        const f16* qp0 = Qp + (size_t)(bT + r0) * qstr + h * 64;
        const f16* qp1 = Qp + (size_t)(bT + r1) * qstr + h * 64;
#pragma unroll
        for (int i = 0; i < 8; ++i) {
            q0[i] = *(const f16x8*)(qp0 + i * 8);
            q1[i] = *(const f16x8*)(qp1 + i * 8);
        }
    }
    float o0[64], o1[64];
#pragma unroll
    for (int d = 0; d < 64; ++d) { o0[d] = 0.f; o1[d] = 0.f; }
    float m0 = -1e30f, l0 = 0.f, m1 = -1e30f, l1 = 0.f;

    const float* mrow = maskp + b * TSEQ;
    const int ktot = CAUSAL ? (qblk + 128) : TSEQ;

    for (int k0 = wv * 32; k0 < ktot; k0 += 128) {
        // stage K (f16, direct to LDS)
#pragma unroll
        for (int i = 0; i < 4; ++i) {
            const int c = i * 64 + ln;
            const f16* g = Kp + (size_t)(bT + k0 + (c >> 3)) * kstr + h * 64 + (c & 7) * 8;
            __builtin_amdgcn_global_load_lds(
                (const __attribute__((address_space(1))) unsigned int*)g,
                (__attribute__((address_space(3))) unsigned int*)(Ks + i * 512), 16, 0, 0);
        }
        // stage V (f16 -> f32 in LDS)
#pragma unroll
        for (int i = 0; i < 4; ++i) {
            const int c = i * 64 + ln;
            const f16x8 vv = *(const f16x8*)(Vp + (size_t)(bT + k0 + (c >> 3)) * vstr + h * 64 + (c & 7) * 8);
            float* dst = Vs + (c >> 3) * 64 + (c & 7) * 8;
#pragma unroll
            for (int e = 0; e < 8; ++e) dst[e] = (float)vv[e];
        }
        const float madj = (1.0f - mrow[k0 + (ln & 31)]) * 3.125e8f;  // (1-m)*1e10/32
        asm volatile("s_waitcnt vmcnt(0) lgkmcnt(0)" ::: "memory");

        for (int j = 0; j < 32; ++j) {
            const int kidx = k0 + j;
            const float madj_j = __shfl(madj, j, 64);
            const f16* krow = Ks + j * 64;
            float d0a = 0.f, d0b = 0.f, d1a = 0.f, d1b = 0.f;
#pragma unroll
            for (int i = 0; i < 8; ++i) {
                const f16x8 kv = *(const f16x8*)(krow + i * 8);
                const f16x2* k2 = (const f16x2*)&kv;
                const f16x2* qa = (const f16x2*)&q0[i];
                const f16x2* qb = (const f16x2*)&q1[i];
                d0a = __builtin_amdgcn_fdot2(qa[0], k2[0], d0a, false);
                d0b = __builtin_amdgcn_fdot2(qa[1], k2[1], d0b, false);
                d0a = __builtin_amdgcn_fdot2(qa[2], k2[2], d0a, false);
                d0b = __builtin_amdgcn_fdot2(qa[3], k2[3], d0b, false);
                d1a = __builtin_amdgcn_fdot2(qb[0], k2[0], d1a, false);
                d1b = __builtin_amdgcn_fdot2(qb[1], k2[1], d1b, false);
                d1a = __builtin_amdgcn_fdot2(qb[2], k2[2], d1a, false);
                d1b = __builtin_amdgcn_fdot2(qb[3], k2[3], d1b, false);
            }
            float s0 = (d0a + d0b) * (1.f / 32.f) - madj_j;
            float s1 = (d1a + d1b) * (1.f / 32.f) - madj_j;
            if (CAUSAL) {
                if (kidx > r0) s0 = -3e38f;
                if (kidx > r1) s1 = -3e38f;
            }
            if (s0 > m0 + 8.f) {
                const float c = __expf(m0 - s0);
                l0 *= c;
#pragma unroll
                for (int d = 0; d < 64; ++d) o0[d] *= c;
                m0 = s0;
            }
            if (s1 > m1 + 8.f) {
                const float c = __expf(m1 - s1);
                l1 *= c;
#pragma unroll
                for (int d = 0; d < 64; ++d) o1[d] *= c;
                m1 = s1;
            }
            const float p0 = __expf(s0 - m0);
            const float p1 = __expf(s1 - m1);
            l0 += p0; l1 += p1;
            const float4* vrow = (const float4*)(Vs + j * 64);
#pragma unroll
            for (int i = 0; i < 16; ++i) {
                const float4 vvv = vrow[i];
                o0[i * 4 + 0] = fmaf(p0, vvv.x, o0[i * 4 + 0]);
                o0[i * 4 + 1] = fmaf(p0, vvv.y, o0[i * 4 + 1]);
                o0[i * 4 + 2] = fmaf(p0, vvv.z, o0[i * 4 + 2]);
                o0[i * 4 + 3] = fmaf(p0, vvv.w, o0[i * 4 + 3]);
                o1[i * 4 + 0] = fmaf(p1, vvv.x, o1[i * 4 + 0]);
                o1[i * 4 + 1] = fmaf(p1, vvv.y, o1[i * 4 + 1]);
                o1[i * 4 + 2] = fmaf(p1, vvv.z, o1[i * 4 + 2]);
                o1[i * 4 + 3] = fmaf(p1, vvv.w, o1[i * 4 + 3]);
            }
        }
    }

    // -------- cross-wave merge (k-split reduction) --------
    __syncthreads();
    float* mlbuf = (float*)smem;            // [2][128][2] f32 (2KB)
    f16*   mobuf = (f16*)(smem + 2048);     // [2][128][64] f16 (32KB)

    if (wv >= 2) {
        const int w = wv - 2;
        mlbuf[(w * 128 + ln) * 2 + 0] = m0; mlbuf[(w * 128 + ln) * 2 + 1] = l0;
        mlbuf[(w * 128 + 64 + ln) * 2 + 0] = m1; mlbuf[(w * 128 + 64 + ln) * 2 + 1] = l1;
        f16* da = mobuf + (w * 128 + ln) * 64;
        f16* db = mobuf + (w * 128 + 64 + ln) * 64;
#pragma unroll
        for (int d = 0; d < 64; ++d) { da[d] = (f16)o0[d]; db[d] = (f16)o1[d]; }
    }
    __syncthreads();
    if (wv < 2) {
        const int w = wv;
        {
            const float mb = mlbuf[(w * 128 + ln) * 2], lb = mlbuf[(w * 128 + ln) * 2 + 1];
            const float M = fmaxf(m0, mb);
            const float ca = __expf(m0 - M), cb = __expf(mb - M);
            const f16* ob = mobuf + (w * 128 + ln) * 64;
            l0 = l0 * ca + lb * cb;
#pragma unroll
            for (int d = 0; d < 64; ++d) o0[d] = o0[d] * ca + (float)ob[d] * cb;
            m0 = M;
        }
        {
            const float mb = mlbuf[(w * 128 + 64 + ln) * 2], lb = mlbuf[(w * 128 + 64 + ln) * 2 + 1];
            const float M = fmaxf(m1, mb);
            const float ca = __expf(m1 - M), cb = __expf(mb - M);
            const f16* ob = mobuf + (w * 128 + 64 + ln) * 64;
            l1 = l1 * ca + lb * cb;
#pragma unroll
            for (int d = 0; d < 64; ++d) o1[d] = o1[d] * ca + (float)ob[d] * cb;
            m1 = M;
        }
    }
    __syncthreads();
    if (wv == 1) {
        mlbuf[ln * 2 + 0] = m0; mlbuf[ln * 2 + 1] = l0;
        mlbuf[(64 + ln) * 2 + 0] = m1; mlbuf[(64 + ln) * 2 + 1] = l1;
        f16* da = mobuf + ln * 64;
        f16* db = mobuf + (64 + ln) * 64;
#pragma unroll
        for (int d = 0; d < 64; ++d) { da[d] = (f16)o0[d]; db[d] = (f16)o1[d]; }
    }
    __syncthreads();
    if (wv == 0) {
        {
            const float mb = mlbuf[ln * 2], lb = mlbuf[ln * 2 + 1];
            const float M = fmaxf(m0, mb);
            const float ca = __expf(m0 - M), cb = __expf(mb - M);
            const f16* ob = mobuf + ln * 64;
            l0 = l0 * ca + lb * cb;
#pragma unroll
            for (int d = 0; d < 64; ++d) o0[d] = o0[d] * ca + (float)ob[d] * cb;
        }
        {
            const float mb = mlbuf[(64 + ln) * 2], lb = mlbuf[(64 + ln) * 2 + 1];
            const float M = fmaxf(m1, mb);
            const float ca = __expf(m1 - M), cb = __expf(mb - M);
            const f16* ob = mobuf + (64 + ln) * 64;
            l1 = l1 * ca + lb * cb;
#pragma unroll
            for (int d = 0; d < 64; ++d) o1[d] = o1[d] * ca + (float)ob[d] * cb;
        }
        const float i0 = 1.f / l0, i1 = 1.f / l1;
        f16* op0 = Op + (size_t)(bT + r0) * DMODEL + h * 64;
        f16* op1 = Op + (size_t)(bT + r1) * DMODEL + h * 64;
#pragma unroll
        for (int i = 0; i < 8; ++i) {
            f16x8 w0, w1;
#pragma unroll
            for (int e = 0; e < 8; ++e) {
                w0[e] = (_Float16)(o0[i * 8 + e] * i0);
                w1[e] = (_Float16)(o1[i * 8 + e] * i1);
            }
            *(f16x8*)(op0 + i * 8) = w0;
            *(f16x8*)(op1 + i * 8) = w1;
        }
    }
}

// ---------------------------------------------------------------------------
// LayerNorm: unbiased var (/(D-1)), eps added to STD. f16 in, f16 or f32 out.
// ---------------------------------------------------------------------------
__inline__ __device__ float block_sum256(float v, float* sm)
{
#pragma unroll
    for (int off = 32; off > 0; off >>= 1) v += __shfl_down(v, off, 64);
    const int lane = threadIdx.x & 63, w = threadIdx.x >> 6;
    if (lane == 0) sm[w] = v;
    __syncthreads();
    const float r = sm[0] + sm[1] + sm[2] + sm[3];
    __syncthreads();
    return r;
}

template<bool F32OUT>
__global__ __launch_bounds__(256)
void ln_kernel(const f16* __restrict__ X, const float* __restrict__ g,
               const float* __restrict__ be, void* __restrict__ Yv)
{
    __shared__ float sm[4];
    const int row = blockIdx.x;
    const size_t base = (size_t)row * DMODEL + threadIdx.x * 4;
    const f16x4 xv = *(const f16x4*)(X + base);
    float x[4] = {(float)xv[0], (float)xv[1], (float)xv[2], (float)xv[3]};

    float s = x[0] + x[1] + x[2] + x[3];
    s = block_sum256(s, sm);
    const float mean = s * (1.0f / (float)DMODEL);

    float dx[4] = {x[0] - mean, x[1] - mean, x[2] - mean, x[3] - mean};
    float s2 = dx[0] * dx[0] + dx[1] * dx[1] + dx[2] * dx[2] + dx[3] * dx[3];
    s2 = block_sum256(s2, sm);
    const float rs = 1.0f / (sqrtf(s2 * (1.0f / (float)(DMODEL - 1))) + 1e-6f);

    const float4 gv = *(const float4*)(g + threadIdx.x * 4);
    const float4 bv = *(const float4*)(be + threadIdx.x * 4);
    const float y0 = gv.x * dx[0] * rs + bv.x;
    const float y1 = gv.y * dx[1] * rs + bv.y;
    const float y2 = gv.z * dx[2] * rs + bv.z;
    const float y3 = gv.w * dx[3] * rs + bv.w;
    if (F32OUT) {
        float4 y = {y0, y1, y2, y3};
        *(float4*)((float*)Yv + base) = y;
    } else {
        f16x4 y; y[0] = (_Float16)y0; y[1] = (_Float16)y1; y[2] = (_Float16)y2; y[3] = (_Float16)y3;
        *(f16x4*)((f16*)Yv + base) = y;
    }
}

// ---------------------------------------------------------------------------
extern "C" void kernel_launch(void* const* d_in, const int* in_sizes, int n_in,
                              void* d_out, int out_size, void* d_ws, size_t ws_size,
                              hipStream_t stream)
{
    (void)in_sizes; (void)n_in; (void)out_size; (void)ws_size;

    const float* x        = (const float*)d_in[0];
    const float* enc      = (const float*)d_in[1];
    const float* mask_src = (const float*)d_in[2];
    const float* mask_trg = (const float*)d_in[3];
    const float* sa_wq = (const float*)d_in[4];  const float* sa_bq = (const float*)d_in[5];
    const float* sa_wk = (const float*)d_in[6];  const float* sa_bk = (const float*)d_in[7];
    const float* sa_wv = (const float*)d_in[8];  const float* sa_bv = (const float*)d_in[9];
    const float* sa_wo = (const float*)d_in[10]; const float* sa_bo = (const float*)d_in[11];
    const float* sa_g  = (const float*)d_in[12]; const float* sa_b  = (const float*)d_in[13];
    const float* ca_wq = (const float*)d_in[14]; const float* ca_bq = (const float*)d_in[15];
    const float* ca_wk = (const float*)d_in[16]; const float* ca_bk = (const float*)d_in[17];
    const float* ca_wv = (const float*)d_in[18]; const float* ca_bv = (const float*)d_in[19];
    const float* ca_wo = (const float*)d_in[20]; const float* ca_bo = (const float*)d_in[21];
    const float* ca_g  = (const float*)d_in[22]; const float* ca_b  = (const float*)d_in[23];
    const float* ff_w1 = (const float*)d_in[24]; const float* ff_b1 = (const float*)d_in[25];
    const float* ff_w2 = (const float*)d_in[26]; const float* ff_b2 = (const float*)d_in[27];
    const float* ff_g  = (const float*)d_in[28]; const float* ff_b  = (const float*)d_in[29];

    // workspace map (f16 elems unless noted):
    //  Wh  [0, 4M)        8MB  weight slot (reused per GEMM)
    //  G   [4M, 20M)     32MB  QKV-packed / Q2+KV2 / FF1-out
    //  S0..S5 at 20M+i*4M 8MB each (48MB)
    //  Bias: fp32, byte offset 88MB, 16KB
    f16* ws = (f16*)d_ws;
    const size_t MEG = 1024 * 1024;
    f16* Wh = ws;
    f16* G  = ws + 4 * MEG;
    f16* S0 = ws + 20 * MEG;
    f16* S1 = ws + 24 * MEG;
    f16* S2 = ws + 28 * MEG;
    f16* S3 = ws + 32 * MEG;
    f16* S4 = ws + 36 * MEG;
    f16* S5 = ws + 40 * MEG;
    float* Bias = (float*)((char*)d_ws + 88 * MEG);

    const int NACT = MROWS * DMODEL;   // 4M
    const int NW   = DMODEL * DMODEL;  // 1M

    dim3 blk(256);
    const int cvAct = NACT / 2048, cvW = NW / 2048, cvFF = (4 * NW) / 2048;
    dim3 gQKV(3072 / 128, MROWS / 128);
    dim3 gN64(DMODEL / 64, MROWS / 128);
    dim3 gKV(2048 / 128, MROWS / 128);
    dim3 gFF1(HFF / 128, MROWS / 128);
    dim3 agrid(TSEQ / 128, BATCH * NHEAD);

    // ---- self-attention (causal) ----
    cvt_f32_f16<<<cvAct, blk, 0, stream>>>(x, S0, NACT);
    cvt_f32_f16<<<cvAct, blk, 0, stream>>>(enc, S1, NACT);
    cvt_f32_f16<<<cvW, blk, 0, stream>>>(sa_wq, Wh, NW);
    cvt_f32_f16<<<cvW, blk, 0, stream>>>(sa_wk, Wh + 1 * MEG, NW);
    cvt_f32_f16<<<cvW, blk, 0, stream>>>(sa_wv, Wh + 2 * MEG, NW);
    hipMemcpyAsync(Bias + 0,    sa_bq, 4096, hipMemcpyDeviceToDevice, stream);
    hipMemcpyAsync(Bias + 1024, sa_bk, 4096, hipMemcpyDeviceToDevice, stream);
    hipMemcpyAsync(Bias + 2048, sa_bv, 4096, hipMemcpyDeviceToDevice, stream);
    hgemm<128, false, false><<<gQKV, blk, 0, stream>>>(S0, Wh, Bias, nullptr, G, MROWS, 3072, DMODEL);
    attn<true><<<agrid, blk, 0, stream>>>(G, 3072, G + 1024, 3072, G + 2048, 3072, mask_trg, S2);
    cvt_f32_f16<<<cvW, blk, 0, stream>>>(sa_wo, Wh, NW);
    hipMemcpyAsync(Bias, sa_bo, 4096, hipMemcpyDeviceToDevice, stream);
    hgemm<64, true, false><<<gN64, blk, 0, stream>>>(S2, Wh, Bias, S0, S3, MROWS, DMODEL, DMODEL);
    ln_kernel<false><<<MROWS, blk, 0, stream>>>(S3, sa_g, sa_b, S4);   // H1 = S4

    // ---- cross-attention ----
    cvt_f32_f16<<<cvW, blk, 0, stream>>>(ca_wq, Wh, NW);
    hipMemcpyAsync(Bias, ca_bq, 4096, hipMemcpyDeviceToDevice, stream);
    hgemm<64, false, false><<<gN64, blk, 0, stream>>>(S4, Wh, Bias, nullptr, G, MROWS, DMODEL, DMODEL);  // Q2
    cvt_f32_f16<<<cvW, blk, 0, stream>>>(ca_wk, Wh, NW);
    cvt_f32_f16<<<cvW, blk, 0, stream>>>(ca_wv, Wh + 1 * MEG, NW);
    hipMemcpyAsync(Bias + 0,    ca_bk, 4096, hipMemcpyDeviceToDevice, stream);
    hipMemcpyAsync(Bias + 1024, ca_bv, 4096, hipMemcpyDeviceToDevice, stream);
    hgemm<128, false, false><<<gKV, blk, 0, stream>>>(S1, Wh, Bias, nullptr, G + 4 * MEG, MROWS, 2048, DMODEL); // K2V2
    attn<false><<<agrid, blk, 0, stream>>>(G, 1024, G + 4 * MEG, 2048, G + 4 * MEG + 1024, 2048, mask_src, S2);
    cvt_f32_f16<<<cvW, blk, 0, stream>>>(ca_wo, Wh, NW);
    hipMemcpyAsync(Bias, ca_bo, 4096, hipMemcpyDeviceToDevice, stream);
    hgemm<64, true, false><<<gN64, blk, 0, stream>>>(S2, Wh, Bias, S4, S3, MROWS, DMODEL, DMODEL);
    ln_kernel<false><<<MROWS, blk, 0, stream>>>(S3, ca_g, ca_b, S5);   // H2 = S5

    // ---- feedforward ----
    cvt_f32_f16<<<cvFF, blk, 0, stream>>>(ff_w1, Wh, 4 * NW);
    hipMemcpyAsync(Bias, ff_b1, 16384, hipMemcpyDeviceToDevice, stream);
    hgemm<128, false, true><<<gFF1, blk, 0, stream>>>(S5, Wh, Bias, nullptr, G, MROWS, HFF, DMODEL);
    cvt_f32_f16<<<cvFF, blk, 0, stream>>>(ff_w2, Wh, 4 * NW);
    hipMemcpyAsync(Bias, ff_b2, 4096, hipMemcpyDeviceToDevice, stream);
    hgemm<64, true, false><<<gN64, blk, 0, stream>>>(G, Wh, Bias, S5, S3, MROWS, DMODEL, HFF);
    ln_kernel<true><<<MROWS, blk, 0, stream>>>(S3, ff_g, ff_b, d_out);
}

// Round 3
// 574.367 us; speedup vs baseline: 6.2153x; 1.6265x over previous
//
#include <hip/hip_runtime.h>
#include <hip/hip_bf16.h>
#include <math.h>
#include <stdint.h>

#define BATCH   4
#define TSEQ    1024
#define DMODEL  1024
#define NHEAD   16
#define DHEAD   64
#define HFF     4096
#define MROWS   (BATCH * TSEQ)   // 4096

typedef _Float16 f16;
typedef __attribute__((ext_vector_type(2))) _Float16 f16x2;
typedef __attribute__((ext_vector_type(4))) _Float16 f16x4;
typedef __attribute__((ext_vector_type(8))) _Float16 f16x8;
typedef __attribute__((ext_vector_type(4))) float    f32x4;

// ---------------------------------------------------------------------------
// fp32 -> f16 conversion (vectorized, 8 elems/thread)
// ---------------------------------------------------------------------------
__global__ __launch_bounds__(256)
void cvt_f32_f16(const float* __restrict__ in, f16* __restrict__ out, int n)
{
    const int i = (blockIdx.x * 256 + threadIdx.x) * 8;
    if (i < n) {
        const float4 a = *(const float4*)(in + i);
        const float4 b = *(const float4*)(in + i + 4);
        f16x8 o;
        o[0] = (_Float16)a.x; o[1] = (_Float16)a.y; o[2] = (_Float16)a.z; o[3] = (_Float16)a.w;
        o[4] = (_Float16)b.x; o[5] = (_Float16)b.y; o[6] = (_Float16)b.z; o[7] = (_Float16)b.w;
        *(f16x8*)(out + i) = o;
    }
}

// ---------------------------------------------------------------------------
// f16 MFMA GEMM: C[M,N](f16) = A[M,K](f16) @ W[N,K]^T(f16) + bias (+res)(+relu)
// Tile 128 x TN, BK=32, 256 threads = 4 waves (2x2), 2-phase LDS double-buffer,
// staging via global_load_lds width=16. mfma_f32_16x16x32_f16.  (validated R2)
// ---------------------------------------------------------------------------
template<int TN, bool RES, bool RELU>
__global__ __launch_bounds__(256, 2)
void hgemm(const f16* __restrict__ A, const f16* __restrict__ Wt,
           const float* __restrict__ bias, const f16* __restrict__ Rm,
           f16* __restrict__ C, int M, int N, int K)
{
    constexpr int TM = 128, TK = 32;
    constexpr int NB = TN / 32;
    constexpr int AISS = (TM * TK) / (256 * 8);
    constexpr int BISS = (TN * TK) / (256 * 8);
    __shared__ alignas(16) f16 As[2][TM * TK];
    __shared__ alignas(16) f16 Bs[2][TN * TK];

    const int t = threadIdx.x, ln = t & 63, wv = t >> 6;
    const int wr = wv >> 1, wc = wv & 1;
    const size_t m0 = (size_t)blockIdx.y * TM, n0 = (size_t)blockIdx.x * TN;

    f32x4 acc[4][NB];
#pragma unroll
    for (int i = 0; i < 4; ++i)
#pragma unroll
        for (int j = 0; j < NB; ++j) acc[i][j] = (f32x4){0.f, 0.f, 0.f, 0.f};

    const f16* Ag = A + (m0 + (t >> 2)) * (size_t)K + (t & 3) * 8;
    const f16* Bg = Wt + (n0 + (t >> 2)) * (size_t)K + (t & 3) * 8;

    auto stage = [&](int buf, int k0) {
#pragma unroll
        for (int i = 0; i < AISS; ++i)
            __builtin_amdgcn_global_load_lds(
                (const __attribute__((address_space(1))) unsigned int*)(Ag + (size_t)(i * 64) * K + k0),
                (__attribute__((address_space(3))) unsigned int*)(&As[buf][(i * 256 + wv * 64) * 8]),
                16, 0, 0);
#pragma unroll
        for (int i = 0; i < BISS; ++i)
            __builtin_amdgcn_global_load_lds(
                (const __attribute__((address_space(1))) unsigned int*)(Bg + (size_t)(i * 64) * K + k0),
                (__attribute__((address_space(3))) unsigned int*)(&Bs[buf][(i * 256 + wv * 64) * 8]),
                16, 0, 0);
    };

    stage(0, 0);
    __syncthreads();
    int buf = 0;
    for (int k0 = 0; k0 < K; k0 += TK) {
        if (k0 + TK < K) stage(buf ^ 1, k0 + TK);
        f16x8 af[4], bf[NB];
        const f16* Ab = As[buf];
        const f16* Bb = Bs[buf];
#pragma unroll
        for (int i = 0; i < 4; ++i)
            af[i] = *(const f16x8*)(Ab + (wr * 64 + i * 16 + (ln & 15)) * TK + (ln >> 4) * 8);
#pragma unroll
        for (int j = 0; j < NB; ++j)
            bf[j] = *(const f16x8*)(Bb + (wc * (TN / 2) + j * 16 + (ln & 15)) * TK + (ln >> 4) * 8);
#pragma unroll
        for (int i = 0; i < 4; ++i)
#pragma unroll
            for (int j = 0; j < NB; ++j)
                acc[i][j] = __builtin_amdgcn_mfma_f32_16x16x32_f16(af[i], bf[j], acc[i][j], 0, 0, 0);
        __syncthreads();
        buf ^= 1;
    }

    const int colbase = (int)n0 + wc * (TN / 2) + (ln & 15);
    const int rowbase = (int)m0 + wr * 64 + (ln >> 4) * 4;
#pragma unroll
    for (int i = 0; i < 4; ++i) {
#pragma unroll
        for (int j = 0; j < NB; ++j) {
            const int col = colbase + j * 16;
            const float bj = bias[col];
#pragma unroll
            for (int r = 0; r < 4; ++r) {
                const int row = rowbase + i * 16 + r;
                float v = acc[i][j][r] + bj;
                if (RES) v += (float)Rm[(size_t)row * N + col];
                if (RELU) v = fmaxf(v, 0.f);
                C[(size_t)row * N + col] = (f16)v;
            }
        }
    }
}

// ---------------------------------------------------------------------------
// MFMA flash attention, f16 in/out, fp32 softmax/accum.
// Block = 256 thr = 4 waves, covers 64 q-rows (wave w owns rows q0+w*16..+15).
// KV tile = 64 keys. Swapped operands: S^T = mfma(K, Q) so softmax is in-lane;
// O^T = mfma(V^T, P^T). K stored [key][d], V stored transposed [d][key], both
// XOR-swizzled (idx ^= (row&7)*8 on 64-f16 rows) -> conflict-free ds_read_b128.
// P round-trips per-wave LDS buffer [q][key] (swizzled). T14 staging split.
// ---------------------------------------------------------------------------
template<bool CAUSAL>
__global__ __launch_bounds__(256, 2)
void attn_mfma(const f16* __restrict__ Qp, int qstr,
               const f16* __restrict__ Kp, int kstr,
               const f16* __restrict__ Vp, int vstr,
               const float* __restrict__ maskp,
               f16* __restrict__ Op)
{
    __shared__ alignas(16) f16 Ks[64 * 64];     // [key][d] swizzled
    __shared__ alignas(16) f16 Vt[64 * 64];     // [d][key] swizzled (V^T)
    __shared__ alignas(16) f16 Ps[4][16 * 64];  // per-wave P [q][key] swizzled
    __shared__ alignas(16) float Msk[64];

    const int t = threadIdx.x, l = t & 63, wv = t >> 6;
    const int g = l >> 4, lq = l & 15, a = l & 7;
    const int bh = blockIdx.y, b = bh >> 4, h = bh & 15;
    const int q0 = blockIdx.x * 64;
    const int q0w = q0 + wv * 16;
    const int bT = b * TSEQ;

    // Q fragment (B-operand): col = q = lq, k = s*32 + g*8 + e  (held in regs)
    f16x8 qf[2];
    {
        const f16* qp = Qp + (size_t)(bT + q0w + lq) * qstr + h * 64 + g * 8;
        qf[0] = *(const f16x8*)(qp);
        qf[1] = *(const f16x8*)(qp + 32);
    }

    f32x4 oacc[4];
#pragma unroll
    for (int i = 0; i < 4; ++i) oacc[i] = (f32x4){0.f, 0.f, 0.f, 0.f};
    float mrun = -1e30f, lrun = 0.f;

    const float* mrow = maskp + b * TSEQ;
    const int kend = CAUSAL ? (q0 + 64) : TSEQ;
    const int qmaxw = q0w + 15;

    // staging registers (reg double-buffer, single LDS buffer)
    f16x8 kr0, kr1, vr0, vr1;
    float mreg = 0.f;
    const int kkey = t >> 3, kd8 = t & 7;      // K slots: (key, key+32) x d-chunk

    auto issue_loads = [&](int k0) {
        kr0 = *(const f16x8*)(Kp + (size_t)(bT + k0 + kkey) * kstr + h * 64 + kd8 * 8);
        kr1 = *(const f16x8*)(Kp + (size_t)(bT + k0 + 32 + kkey) * kstr + h * 64 + kd8 * 8);
        vr0 = *(const f16x8*)(Vp + (size_t)(bT + k0 + l) * vstr + h * 64 + wv * 8);
        vr1 = *(const f16x8*)(Vp + (size_t)(bT + k0 + l) * vstr + h * 64 + (4 + wv) * 8);
        if (t < 64) mreg = mrow[k0 + t];
    };
    auto write_stage = [&]() {
        *(f16x8*)&Ks[kkey * 64 + ((kd8 * 8) ^ ((kkey & 7) * 8))] = kr0;
        const int k2 = kkey + 32;
        *(f16x8*)&Ks[k2 * 64 + ((kd8 * 8) ^ ((k2 & 7) * 8))] = kr1;
#pragma unroll
        for (int e = 0; e < 8; ++e) {
            const int d0 = wv * 8 + e;          // V^T row; d0&7 == e
            const int d1 = (4 + wv) * 8 + e;
            Vt[d0 * 64 + (l ^ (e * 8))] = vr0[e];
            Vt[d1 * 64 + (l ^ (e * 8))] = vr1[e];
        }
        if (t < 64) Msk[t] = mreg;
    };

    issue_loads(0);
    write_stage();
    __syncthreads();

    f16* Pw = Ps[wv];

    for (int k0 = 0; k0 < kend; k0 += 64) {
        const int knext = k0 + 64;
        if (knext < kend) issue_loads(knext);

        if (!CAUSAL || k0 <= qmaxw) {
            // ---- S^T = K-tile @ Q^T : 4 key-subtiles of 16 ----
            f32x4 sacc[4];
#pragma unroll
            for (int kt = 0; kt < 4; ++kt) {
                const int row = kt * 16 + lq;
                const int sw = (row & 7) * 8;
                const f16x8 a0 = *(const f16x8*)&Ks[row * 64 + ((g * 8) ^ sw)];
                const f16x8 a1 = *(const f16x8*)&Ks[row * 64 + (((4 + g) * 8) ^ sw)];
                f32x4 z = (f32x4){0.f, 0.f, 0.f, 0.f};
                z = __builtin_amdgcn_mfma_f32_16x16x32_f16(a0, qf[0], z, 0, 0, 0);
                sacc[kt] = __builtin_amdgcn_mfma_f32_16x16x32_f16(a1, qf[1], z, 0, 0, 0);
            }
            // ---- softmax (scores for q=lq live in-lane: 4 tiles x 4 regs) ----
            float p[4][4];
            float tmax = -3.0e38f;
#pragma unroll
            for (int kt = 0; kt < 4; ++kt) {
                const float4 mk = *(const float4*)&Msk[kt * 16 + g * 4];
                const float mka[4] = {mk.x, mk.y, mk.z, mk.w};
#pragma unroll
                for (int r = 0; r < 4; ++r) {
                    float s = sacc[kt][r] * (1.f / 32.f) - (1.f - mka[r]) * 3.125e8f;
                    if (CAUSAL) {
                        const int key = k0 + kt * 16 + g * 4 + r;
                        if (key > q0w + lq) s = -3.0e38f;
                    }
                    p[kt][r] = s;
                    tmax = fmaxf(tmax, s);
                }
            }
            tmax = fmaxf(tmax, __shfl_xor(tmax, 16));
            tmax = fmaxf(tmax, __shfl_xor(tmax, 32));
            const float mnew = fmaxf(mrun, tmax);
            const float corr = __expf(mrun - mnew);
            mrun = mnew;
            lrun *= corr;
#pragma unroll
            for (int i = 0; i < 4; ++i) {
                oacc[i][0] *= corr; oacc[i][1] *= corr;
                oacc[i][2] *= corr; oacc[i][3] *= corr;
            }
            float rsum = 0.f;
#pragma unroll
            for (int kt = 0; kt < 4; ++kt)
#pragma unroll
                for (int r = 0; r < 4; ++r) {
                    const float e = __expf(p[kt][r] - mnew);
                    p[kt][r] = e;
                    rsum += e;
                }
            rsum += __shfl_xor(rsum, 16);
            rsum += __shfl_xor(rsum, 32);
            lrun += rsum;
            // ---- write P (f16) to per-wave LDS in B-frag-ready layout ----
#pragma unroll
            for (int kt = 0; kt < 4; ++kt) {
                f16x4 pv;
                pv[0] = (_Float16)p[kt][0]; pv[1] = (_Float16)p[kt][1];
                pv[2] = (_Float16)p[kt][2]; pv[3] = (_Float16)p[kt][3];
                const int kb = kt * 16 + g * 4;
                *(f16x4*)&Pw[lq * 64 + (kb ^ (a * 8))] = pv;
            }
            // ---- O^T += V^T @ P^T ----
            const f16x8 pf0 = *(const f16x8*)&Pw[lq * 64 + ((g * 8) ^ (a * 8))];
            const f16x8 pf1 = *(const f16x8*)&Pw[lq * 64 + (((4 + g) * 8) ^ (a * 8))];
#pragma unroll
            for (int dt = 0; dt < 4; ++dt) {
                const int row = dt * 16 + lq;
                const int sw = (row & 7) * 8;
                const f16x8 v0 = *(const f16x8*)&Vt[row * 64 + ((g * 8) ^ sw)];
                const f16x8 v1 = *(const f16x8*)&Vt[row * 64 + (((4 + g) * 8) ^ sw)];
                oacc[dt] = __builtin_amdgcn_mfma_f32_16x16x32_f16(v0, pf0, oacc[dt], 0, 0, 0);
                oacc[dt] = __builtin_amdgcn_mfma_f32_16x16x32_f16(v1, pf1, oacc[dt], 0, 0, 0);
            }
        }

        __syncthreads();
        if (knext < kend) write_stage();
        __syncthreads();
    }

    // ---- epilogue: divide by l, transpose via per-wave LDS, coalesced store ----
    const float inv = 1.f / lrun;
#pragma unroll
    for (int dt = 0; dt < 4; ++dt) {
        f16x4 ov;
        ov[0] = (_Float16)(oacc[dt][0] * inv); ov[1] = (_Float16)(oacc[dt][1] * inv);
        ov[2] = (_Float16)(oacc[dt][2] * inv); ov[3] = (_Float16)(oacc[dt][3] * inv);
        const int db = dt * 16 + g * 4;
        *(f16x4*)&Pw[lq * 64 + (db ^ (a * 8))] = ov;    // [q][d] swizzled
    }
#pragma unroll
    for (int i = 0; i < 2; ++i) {
        const int c = i * 64 + l;
        const int row = c >> 3, c8 = c & 7;
        const f16x8 ov = *(const f16x8*)&Pw[row * 64 + ((c8 * 8) ^ ((row & 7) * 8))];
        *(f16x8*)(Op + (size_t)(bT + q0w + row) * DMODEL + h * 64 + c8 * 8) = ov;
    }
}

// ---------------------------------------------------------------------------
// LayerNorm: unbiased var (/(D-1)), eps added to STD. f16 in, f16 or f32 out.
// ---------------------------------------------------------------------------
__inline__ __device__ float block_sum256(float v, float* sm)
{
#pragma unroll
    for (int off = 32; off > 0; off >>= 1) v += __shfl_down(v, off, 64);
    const int lane = threadIdx.x & 63, w = threadIdx.x >> 6;
    if (lane == 0) sm[w] = v;
    __syncthreads();
    const float r = sm[0] + sm[1] + sm[2] + sm[3];
    __syncthreads();
    return r;
}

template<bool F32OUT>
__global__ __launch_bounds__(256)
void ln_kernel(const f16* __restrict__ X, const float* __restrict__ g,
               const float* __restrict__ be, void* __restrict__ Yv)
{
    __shared__ float sm[4];
    const int row = blockIdx.x;
    const size_t base = (size_t)row * DMODEL + threadIdx.x * 4;
    const f16x4 xv = *(const f16x4*)(X + base);
    float x[4] = {(float)xv[0], (float)xv[1], (float)xv[2], (float)xv[3]};

    float s = x[0] + x[1] + x[2] + x[3];
    s = block_sum256(s, sm);
    const float mean = s * (1.0f / (float)DMODEL);

    float dx[4] = {x[0] - mean, x[1] - mean, x[2] - mean, x[3] - mean};
    float s2 = dx[0] * dx[0] + dx[1] * dx[1] + dx[2] * dx[2] + dx[3] * dx[3];
    s2 = block_sum256(s2, sm);
    const float rs = 1.0f / (sqrtf(s2 * (1.0f / (float)(DMODEL - 1))) + 1e-6f);

    const float4 gv = *(const float4*)(g + threadIdx.x * 4);
    const float4 bv = *(const float4*)(be + threadIdx.x * 4);
    const float y0 = gv.x * dx[0] * rs + bv.x;
    const float y1 = gv.y * dx[1] * rs + bv.y;
    const float y2 = gv.z * dx[2] * rs + bv.z;
    const float y3 = gv.w * dx[3] * rs + bv.w;
    if (F32OUT) {
        float4 y = {y0, y1, y2, y3};
        *(float4*)((float*)Yv + base) = y;
    } else {
        f16x4 y; y[0] = (_Float16)y0; y[1] = (_Float16)y1; y[2] = (_Float16)y2; y[3] = (_Float16)y3;
        *(f16x4*)((f16*)Yv + base) = y;
    }
}

// ---------------------------------------------------------------------------
extern "C" void kernel_launch(void* const* d_in, const int* in_sizes, int n_in,
                              void* d_out, int out_size, void* d_ws, size_t ws_size,
                              hipStream_t stream)
{
    (void)in_sizes; (void)n_in; (void)out_size; (void)ws_size;

    const float* x        = (const float*)d_in[0];
    const float* enc      = (const float*)d_in[1];
    const float* mask_src = (const float*)d_in[2];
    const float* mask_trg = (const float*)d_in[3];
    const float* sa_wq = (const float*)d_in[4];  const float* sa_bq = (const float*)d_in[5];
    const float* sa_wk = (const float*)d_in[6];  const float* sa_bk = (const float*)d_in[7];
    const float* sa_wv = (const float*)d_in[8];  const float* sa_bv = (const float*)d_in[9];
    const float* sa_wo = (const float*)d_in[10]; const float* sa_bo = (const float*)d_in[11];
    const float* sa_g  = (const float*)d_in[12]; const float* sa_b  = (const float*)d_in[13];
    const float* ca_wq = (const float*)d_in[14]; const float* ca_bq = (const float*)d_in[15];
    const float* ca_wk = (const float*)d_in[16]; const float* ca_bk = (const float*)d_in[17];
    const float* ca_wv = (const float*)d_in[18]; const float* ca_bv = (const float*)d_in[19];
    const float* ca_wo = (const float*)d_in[20]; const float* ca_bo = (const float*)d_in[21];
    const float* ca_g  = (const float*)d_in[22]; const float* ca_b  = (const float*)d_in[23];
    const float* ff_w1 = (const float*)d_in[24]; const float* ff_b1 = (const float*)d_in[25];
    const float* ff_w2 = (const float*)d_in[26]; const float* ff_b2 = (const float*)d_in[27];
    const float* ff_g  = (const float*)d_in[28]; const float* ff_b  = (const float*)d_in[29];

    f16* ws = (f16*)d_ws;
    const size_t MEG = 1024 * 1024;
    f16* Wh = ws;
    f16* G  = ws + 4 * MEG;
    f16* S0 = ws + 20 * MEG;
    f16* S1 = ws + 24 * MEG;
    f16* S2 = ws + 28 * MEG;
    f16* S3 = ws + 32 * MEG;
    f16* S4 = ws + 36 * MEG;
    f16* S5 = ws + 40 * MEG;
    float* Bias = (float*)((char*)d_ws + 88 * MEG);

    const int NACT = MROWS * DMODEL;   // 4M
    const int NW   = DMODEL * DMODEL;  // 1M

    dim3 blk(256);
    const int cvAct = NACT / 2048, cvW = NW / 2048, cvFF = (4 * NW) / 2048;
    dim3 gQKV(3072 / 128, MROWS / 128);
    dim3 gN64(DMODEL / 64, MROWS / 128);
    dim3 gKV(2048 / 128, MROWS / 128);
    dim3 gFF1(HFF / 128, MROWS / 128);
    dim3 agrid(TSEQ / 64, BATCH * NHEAD);

    // ---- self-attention (causal) ----
    cvt_f32_f16<<<cvAct, blk, 0, stream>>>(x, S0, NACT);
    cvt_f32_f16<<<cvAct, blk, 0, stream>>>(enc, S1, NACT);
    cvt_f32_f16<<<cvW, blk, 0, stream>>>(sa_wq, Wh, NW);
    cvt_f32_f16<<<cvW, blk, 0, stream>>>(sa_wk, Wh + 1 * MEG, NW);
    cvt_f32_f16<<<cvW, blk, 0, stream>>>(sa_wv, Wh + 2 * MEG, NW);
    hipMemcpyAsync(Bias + 0,    sa_bq, 4096, hipMemcpyDeviceToDevice, stream);
    hipMemcpyAsync(Bias + 1024, sa_bk, 4096, hipMemcpyDeviceToDevice, stream);
    hipMemcpyAsync(Bias + 2048, sa_bv, 4096, hipMemcpyDeviceToDevice, stream);
    hgemm<128, false, false><<<gQKV, blk, 0, stream>>>(S0, Wh, Bias, nullptr, G, MROWS, 3072, DMODEL);
    attn_mfma<true><<<agrid, blk, 0, stream>>>(G, 3072, G + 1024, 3072, G + 2048, 3072, mask_trg, S2);
    cvt_f32_f16<<<cvW, blk, 0, stream>>>(sa_wo, Wh, NW);
    hipMemcpyAsync(Bias, sa_bo, 4096, hipMemcpyDeviceToDevice, stream);
    hgemm<64, true, false><<<gN64, blk, 0, stream>>>(S2, Wh, Bias, S0, S3, MROWS, DMODEL, DMODEL);
    ln_kernel<false><<<MROWS, blk, 0, stream>>>(S3, sa_g, sa_b, S4);   // H1 = S4

    // ---- cross-attention ----
    cvt_f32_f16<<<cvW, blk, 0, stream>>>(ca_wq, Wh, NW);
    hipMemcpyAsync(Bias, ca_bq, 4096, hipMemcpyDeviceToDevice, stream);
    hgemm<64, false, false><<<gN64, blk, 0, stream>>>(S4, Wh, Bias, nullptr, G, MROWS, DMODEL, DMODEL);  // Q2
    cvt_f32_f16<<<cvW, blk, 0, stream>>>(ca_wk, Wh, NW);
    cvt_f32_f16<<<cvW, blk, 0, stream>>>(ca_wv, Wh + 1 * MEG, NW);
    hipMemcpyAsync(Bias + 0,    ca_bk, 4096, hipMemcpyDeviceToDevice, stream);
    hipMemcpyAsync(Bias + 1024, ca_bv, 4096, hipMemcpyDeviceToDevice, stream);
    hgemm<128, false, false><<<gKV, blk, 0, stream>>>(S1, Wh, Bias, nullptr, G + 4 * MEG, MROWS, 2048, DMODEL); // K2V2
    attn_mfma<false><<<agrid, blk, 0, stream>>>(G, 1024, G + 4 * MEG, 2048, G + 4 * MEG + 1024, 2048, mask_src, S2);
    cvt_f32_f16<<<cvW, blk, 0, stream>>>(ca_wo, Wh, NW);
    hipMemcpyAsync(Bias, ca_bo, 4096, hipMemcpyDeviceToDevice, stream);
    hgemm<64, true, false><<<gN64, blk, 0, stream>>>(S2, Wh, Bias, S4, S3, MROWS, DMODEL, DMODEL);
    ln_kernel<false><<<MROWS, blk, 0, stream>>>(S3, ca_g, ca_b, S5);   // H2 = S5

    // ---- feedforward ----
    cvt_f32_f16<<<cvFF, blk, 0, stream>>>(ff_w1, Wh, 4 * NW);
    hipMemcpyAsync(Bias, ff_b1, 16384, hipMemcpyDeviceToDevice, stream);
    hgemm<128, false, true><<<gFF1, blk, 0, stream>>>(S5, Wh, Bias, nullptr, G, MROWS, HFF, DMODEL);
    cvt_f32_f16<<<cvFF, blk, 0, stream>>>(ff_w2, Wh, 4 * NW);
    hipMemcpyAsync(Bias, ff_b2, 4096, hipMemcpyDeviceToDevice, stream);
    hgemm<64, true, false><<<gN64, blk, 0, stream>>>(G, Wh, Bias, S5, S3, MROWS, DMODEL, HFF);
    ln_kernel<true><<<MROWS, blk, 0, stream>>>(S3, ff_g, ff_b, d_out);
}